// Round 1
// baseline (788.556 us; speedup 1.0000x reference)
//
#include <hip/hip_runtime.h>

#define NN 4096
#define BB 4
#define FF 64

typedef __attribute__((ext_vector_type(8))) short short8;
typedef __attribute__((ext_vector_type(4))) float f32x4;

__device__ inline unsigned short f2bf(float f) {
    unsigned int u = __float_as_uint(f);
    u += 0x7fffu + ((u >> 16) & 1u);   // RNE; inputs finite so no NaN handling needed
    return (unsigned short)(u >> 16);
}

// Kernel 1: Zt[i][b][f][k] = (X[b] @ w_i)[k][f], stored transposed (f-major) in bf16.
// Grid: 256 blocks (b*64 + ktile), 256 threads.
__global__ __launch_bounds__(256) void prep_z(
    const float* __restrict__ X,
    const float* __restrict__ w0, const float* __restrict__ w1, const float* __restrict__ w2,
    unsigned short* __restrict__ Zt)
{
    __shared__ float Xs[64][68];
    __shared__ unsigned short Zts[64][72];
    const int blk = blockIdx.x;
    const int b = blk >> 6;
    const int k0 = (blk & 63) << 6;
    const int t = threadIdx.x;
    {
        const int kk = t >> 2, c4 = t & 3;
        const float* src = X + ((size_t)b * NN + k0 + kk) * FF;
        #pragma unroll
        for (int p = 0; p < 4; ++p) {
            float4 v = *(const float4*)(src + 4 * (c4 + 4 * p));
            *(float4*)&Xs[kk][4 * (c4 + 4 * p)] = v;
        }
    }
    __syncthreads();
    const int lane = t & 63, w = t >> 6;  // wave w handles k-sub rows w*16..w*16+15, lane = f
    const float* ws[3] = {w0, w1, w2};
    for (int i = 0; i < 3; ++i) {
        float acc[16];
        #pragma unroll
        for (int j = 0; j < 16; ++j) acc[j] = 0.f;
        const float* wp = ws[i];
        for (int c = 0; c < 64; ++c) {
            float wv = wp[c * FF + lane];       // coalesced, L1/L2-cached
            #pragma unroll
            for (int j = 0; j < 16; ++j) acc[j] += Xs[w * 16 + j][c] * wv;  // LDS broadcast
        }
        __syncthreads();   // prior store phase finished reading Zts
        #pragma unroll
        for (int j = 0; j < 16; ++j) Zts[lane][w * 16 + j] = f2bf(acc[j]);
        __syncthreads();
        #pragma unroll
        for (int cc = 0; cc < 2; ++cc) {       // coalesced 16B stores of the transposed tile
            int ch = t + cc * 256;
            int f = ch >> 3, o8 = (ch & 7) * 8;
            float4 v = *(const float4*)&Zts[f][o8];
            *(float4*)(Zt + (((size_t)i * BB + b) * FF + f) * NN + k0 + o8) = v;
        }
    }
}

// Kernel 2: out[b][m][f] = relu( sum_i A_i[b] @ Z_i[b] ).
// Grid: 256 blocks (b*64 + mtile), 768 threads = 12 waves; waves [4i..4i+3] handle A_i.
// BM=64, BK=64; register-prefetch of next tile overlaps compute; fp32 A converted to
// bf16 in-register before LDS staging; mfma_f32_16x16x32_bf16, 4 n-tiles per wave.
__global__ __launch_bounds__(768) void gnn_main(
    const float* __restrict__ A0, const float* __restrict__ A1, const float* __restrict__ A2,
    const unsigned short* __restrict__ Zt,
    float* __restrict__ out)
{
    // per group i: As 64x72 bf16 + Zs 64x72 bf16 (row pad +8 -> 144B stride, 16B-aligned,
    // 2-way bank aliasing only, which is free). Total 55296 B. Epilogue reuses as f32 64x68.
    __shared__ unsigned short lds[3 * 2 * 64 * 72];
    const int blk = blockIdx.x;
    const int b = blk >> 6;
    const int m0 = (blk & 63) << 6;
    const int t = threadIdx.x;
    const int lane = t & 63;
    const int wave = t >> 6;
    const int ig = wave >> 2;       // which A matrix (0..2)
    const int w4 = wave & 3;        // 16-row sub-tile within BM=64
    const int gtid = t & 255;       // tid within the 4-wave group

    const float* Ai = (ig == 0) ? A0 : (ig == 1) ? A1 : A2;
    unsigned short* As = lds + ig * (2 * 64 * 72);
    unsigned short* Zs = As + 64 * 72;

    // A staging: thread -> row r = gtid>>2, 4x float4 chunks at k = 4*(gtid&3)+16p
    const int r = gtid >> 2, c4 = gtid & 3;
    const float* Abase = Ai + (size_t)b * NN * NN + (size_t)(m0 + r) * NN;
    // Z staging: 64 f-rows x 128B; 512 16B-chunks over 256 threads, 2 each
    const int zf0 = gtid >> 3, zo0 = (gtid & 7) * 8;
    const int zf1 = (gtid + 256) >> 3, zo1 = ((gtid + 256) & 7) * 8;
    const unsigned short* Zbase = Zt + (((size_t)ig * BB + b) * FF) * NN;
    const unsigned short* Zp0 = Zbase + (size_t)zf0 * NN + zo0;
    const unsigned short* Zp1 = Zbase + (size_t)zf1 * NN + zo1;

    f32x4 acc[4] = {};

    // prologue prefetch (step 0)
    float4 apf[4];
    float4 zpf0, zpf1;
    #pragma unroll
    for (int p = 0; p < 4; ++p) apf[p] = *(const float4*)(Abase + 4 * c4 + 16 * p);
    zpf0 = *(const float4*)Zp0;
    zpf1 = *(const float4*)Zp1;

    // MFMA fragment read addresses (A: m=lane&15, k=(lane>>4)*8+j ; B: n=lane&15, same k)
    const unsigned short* Arow = As + (w4 * 16 + (lane & 15)) * 72 + (lane >> 4) * 8;
    const unsigned short* Zrow = Zs + (lane & 15) * 72 + (lane >> 4) * 8;

    for (int step = 0; step < 64; ++step) {
        __syncthreads();                      // previous compute done with LDS
        #pragma unroll
        for (int p = 0; p < 4; ++p) {
            ushort4 u;
            u.x = f2bf(apf[p].x); u.y = f2bf(apf[p].y);
            u.z = f2bf(apf[p].z); u.w = f2bf(apf[p].w);
            *(ushort4*)(As + r * 72 + 4 * c4 + 16 * p) = u;
        }
        *(float4*)(Zs + zf0 * 72 + zo0) = zpf0;
        *(float4*)(Zs + zf1 * 72 + zo1) = zpf1;
        if (step < 63) {                      // prefetch next tile; latency hidden by compute
            const float* Ab = Abase + (step + 1) * 64;
            #pragma unroll
            for (int p = 0; p < 4; ++p) apf[p] = *(const float4*)(Ab + 4 * c4 + 16 * p);
            zpf0 = *(const float4*)(Zp0 + (step + 1) * 64);
            zpf1 = *(const float4*)(Zp1 + (step + 1) * 64);
        }
        __syncthreads();                      // staging visible
        #pragma unroll
        for (int kh = 0; kh < 2; ++kh) {
            short8 af = *(const short8*)(Arow + kh * 32);
            #pragma unroll
            for (int nt = 0; nt < 4; ++nt) {
                short8 bf = *(const short8*)(Zrow + nt * 16 * 72 + kh * 32);
                acc[nt] = __builtin_amdgcn_mfma_f32_16x16x32_bf16(af, bf, acc[nt], 0, 0, 0);
            }
        }
    }

    // epilogue: sum the three groups' accumulators through LDS, relu, store
    __syncthreads();
    float* Cred = (float*)lds;                // 64 x 68 f32 = 17408 B, fits in group-0 region
    for (int g = 0; g < 3; ++g) {
        if (ig == g) {
            #pragma unroll
            for (int nt = 0; nt < 4; ++nt) {
                #pragma unroll
                for (int j = 0; j < 4; ++j) {
                    // C/D layout: col = lane&15, row = (lane>>4)*4 + j
                    int row = w4 * 16 + (lane >> 4) * 4 + j;
                    int col = nt * 16 + (lane & 15);
                    if (g == 0) Cred[row * 68 + col] = acc[nt][j];
                    else        Cred[row * 68 + col] += acc[nt][j];
                }
            }
        }
        __syncthreads();
    }
    if (ig == 0) {                            // 256 threads write 64x64 f32, coalesced
        float* orow = out + ((size_t)b * NN + m0 + r) * FF;
        #pragma unroll
        for (int p = 0; p < 4; ++p) {
            int c0 = 4 * (c4 + 4 * p);
            float4 v = *(const float4*)&Cred[r * 68 + c0];
            v.x = fmaxf(v.x, 0.f); v.y = fmaxf(v.y, 0.f);
            v.z = fmaxf(v.z, 0.f); v.w = fmaxf(v.w, 0.f);
            *(float4*)(orow + c0) = v;
        }
    }
}

extern "C" void kernel_launch(void* const* d_in, const int* in_sizes, int n_in,
                              void* d_out, int out_size, void* d_ws, size_t ws_size,
                              hipStream_t stream) {
    const float* X  = (const float*)d_in[0];
    const float* A0 = (const float*)d_in[1];
    const float* A1 = (const float*)d_in[2];
    const float* A2 = (const float*)d_in[3];
    const float* w0 = (const float*)d_in[4];
    const float* w1 = (const float*)d_in[5];
    const float* w2 = (const float*)d_in[6];
    float* out = (float*)d_out;
    unsigned short* Zt = (unsigned short*)d_ws;  // 3*4*64*4096 bf16 = 6.3 MB

    prep_z<<<256, 256, 0, stream>>>(X, w0, w1, w2, Zt);
    gnn_main<<<256, 768, 0, stream>>>(A0, A1, A2, Zt, out);
}